// Round 10
// baseline (1941.126 us; speedup 1.0000x reference)
//
#include <hip/hip_runtime.h>
#include <stdint.h>

typedef uint16_t u16;
typedef unsigned long long u64;
typedef __attribute__((ext_vector_type(8))) short short8;   // 8 x bf16 bits (4 VGPRs)
typedef __attribute__((ext_vector_type(4))) float f32x4;

#define SCOPE __HIP_MEMORY_SCOPE_AGENT
#define FSTRIDE 16   // ints per edge flag line (64B): 4 per-wave flags
#define FLD(p) __hip_atomic_load((p), __ATOMIC_RELAXED, SCOPE)
#define FST(p, v) __hip_atomic_store((p), (v), __ATOMIC_RELAXED, SCOPE)

static __device__ __forceinline__ float bf2f(u16 b) {
  union { uint32_t u; float f; } x; x.u = ((uint32_t)b) << 16; return x.f;
}
static __device__ __forceinline__ u16 f2bf(float f) {
  union { float f; uint32_t u; } x; x.f = f;
  uint32_t u = x.u;
  u += 0x7fffu + ((u >> 16) & 1u);   // RTNE
  return (u16)(u >> 16);
}
// inf-safe: exp(+inf)->inf, 1+inf=inf, rcp(inf)=0; exp(-inf)->0.
static __device__ __forceinline__ float sigm(float x) {
  return __builtin_amdgcn_rcpf(1.f + __expf(-x));
}
static __device__ __forceinline__ float tanhf_(float x) {
  return 1.f - 2.f * __builtin_amdgcn_rcpf(1.f + __expf(2.f * x));
}
// LDS-only barrier: does NOT drain vmcnt.
static __device__ __forceinline__ void lds_barrier() {
  asm volatile("s_waitcnt lgkmcnt(0)\n\ts_barrier" ::: "memory");
}
#define DRAIN0() asm volatile("s_waitcnt vmcnt(0)" ::: "memory")
static __device__ __forceinline__ int imin(int a, int b) { return a < b ? a : b; }

// R19: 4 layers/WG (hops 31->15) with weights in REGISTERS — LDS weights gone.
// R17/R18 bug FOUND: LDS weight regions were spaced at HALF their true size
// (layer = 12 tiles x 2 kc x 512 = 12288 u16, offsets stepped 6144) ->
// adjacent layers overwrote each other's z/n-gate tiles -> deterministic
// protocol-independent 9.3e-2 error (identical in both rounds). Correctly
// sized, 4-layer LDS weights need ~200KB: infeasible. Fix: since the gate-
// quarter split (R13), each WAVE uses only 3 tiles/matrix; 2 cells/wave =
// ~30 fragments ~120-170 VGPR -> weights live in registers (addressing is
// identical to R9-R11's register loads, which passed). LDS = hb+xst (~23KB).
// Geometry/protocol = R18 verbatim (independently re-verified): 16 stages x
// 16 batch chunks (8 rows), X = layers {L0,L0+1} step t, Y = {L0+2,L0+3}
// step t-1, 2 lds_barriers/slot, 1KB ring records, R14 chunk flags
// (fneed=ck+2, decoder-last -1, prologue cbase+1, tail cbase+NC), chunk
// probes, zero-padded tile rows 8-15.
// MFMA 16x16x32 bf16 layouts (m89-verified):
//   A-frag: lane holds A[m=lane&15][k=(lane>>4)*8+j]
//   B-frag: lane holds B[k=(lane>>4)*8+j][n=lane&15]  (W row-major (N,K))
//   C/D: reg p -> (row=(lane>>4)*4+p, col=lane&15)
__global__ __launch_bounds__(512, 1) void gru_pipeline(
    const void* ctx_,
    const void* eWih0_, const void* eWih_, const void* eWhh_,
    const void* ebih_,  const void* ebhh_,
    const void* dWih0_, const void* dWih_, const void* dWhh_,
    const void* dbih_,  const void* dbhh_,
    const void* Wo_,    const void* bo_,   void* out_,
    int* __restrict__ pflag, int* __restrict__ cflag,
    u64* __restrict__ ringE, u64* __restrict__ ringD, int RE, int RW)
{
  constexpr int CH = 2;
  const int tid  = threadIdx.x;
  const bool isX = (tid < 256);   // X: layers L0,L0+1 step t; Y: L0+2,L0+3 step t-1
  const int lane = tid & 63;
  const int qg   = (tid >> 6) & 3;  // wave within group
  const int lo   = lane & 15;
  const int hi   = lane >> 4;
  const int blk  = blockIdx.x;
  const int P    = blk >> 4;      // stage 0..15 (layers 4P..4P+3)
  const int g    = blk & 15;      // batch chunk (8 rows)
  const int L0   = 4 * P;
  const int NKC0 = (P == 0) ? 4 : 2;   // k-chunks for the WG's first layer

  __shared__ __align__(16) u16 hb[4][2][16 * 72];
  __shared__ __align__(16) u16 xst[2][16 * 72];
  __shared__ int s_cnt, s_fin, s_cn;
  if (tid == 0) { s_cnt = 0; s_fin = 0; s_cn = 0; }
  for (int i = tid; i < 16 * 72; i += 512) {
#pragma unroll
    for (int j = 0; j < 4; ++j) { hb[j][0][i] = 0; hb[j][1][i] = 0; }
    xst[0][i] = 0; xst[1][i] = 0;
  }
  __syncthreads();
  {  // dtype probe: even u16s of enc_bih
    u16 v = ((const u16*)ebih_)[2 * (tid & 255)];
    int e = (v >> 7) & 0xFF;
    if (e >= 100 && e <= 126 && isX) atomicAdd(&s_cnt, 1);
  }
  __syncthreads();
  const bool bf = (s_cnt >= 128);   // true: bf16 tensors; false: fp32

  auto ld8 = [&](const void* p, int idx) -> short8 {
    if (bf) return *(const short8*)((const u16*)p + idx);
    const float* f = (const float*)p + idx;
    short8 r;
#pragma unroll
    for (int j = 0; j < 8; ++j) r[j] = (short)f2bf(f[j]);
    return r;
  };
  auto ld1 = [&](const void* p, int idx) -> float {
    return bf ? bf2f(((const u16*)p)[idx]) : ((const float*)p)[idx];
  };

  int T[3]; T[0] = qg; T[1] = 4 + qg; T[2] = 8 + qg;

  short8 zf8 = {0,0,0,0,0,0,0,0};
  short8 whF[3][2], whS[3][2];   // Whh fragments for this wave's two cells
  short8 wiF[3][4], wiS[3][4];   // Wih fragments (kc 2..3 used only by P0-X cell0)
  short8 wo[2][2];               // P15 Y only
  float  bov[2] = {0.f, 0.f};
  float brz_[2][2], bin_[2], bhn_[2];   // [0]=first cell, [1]=second
  brz_[0][0]=brz_[0][1]=brz_[1][0]=brz_[1][1]=0.f;
  bin_[0]=bin_[1]=bhn_[0]=bhn_[1]=0.f;
#pragma unroll
  for (int ti = 0; ti < 3; ++ti) {
    whF[ti][0]=zf8; whF[ti][1]=zf8; whS[ti][0]=zf8; whS[ti][1]=zf8;
#pragma unroll
    for (int kc = 0; kc < 4; ++kc) { wiF[ti][kc]=zf8; wiS[ti][kc]=zf8; }
  }
  wo[0][0]=wo[0][1]=wo[1][0]=wo[1][1]=zf8;

  auto load_phase = [&](int ph) {
    const void* WH  = ph ? dWhh_ : eWhh_;
    const void* WIs = ph ? dWih_ : eWih_;
    const void* WI0 = ph ? dWih0_ : eWih0_;
    const void* bi  = ph ? dbih_ : ebih_;
    const void* bh  = ph ? dbhh_ : ebhh_;
    const int lF = L0 + (isX ? 0 : 2);       // this wave's first layer
    const int lS = lF + 1;                   // second layer
    // cell F input weights: layer lF==0 -> Wih0 (K=128); else Wih[lF-1] (K=64)
    const void* WIF  = (lF == 0) ? WI0 : WIs;
    const int   iF   = (lF == 0) ? 0 : (lF - 1) * 192 * 64;
    const int   KF   = (lF == 0) ? 128 : 64;
    const int   nkcF = (lF == 0) ? 4 : 2;
#pragma unroll
    for (int ti = 0; ti < 3; ++ti) {
#pragma unroll
      for (int kc = 0; kc < 2; ++kc) {
        whF[ti][kc] = ld8(WH, lF*192*64 + (T[ti]*16 + lo)*64 + kc*32 + hi*8);
        whS[ti][kc] = ld8(WH, lS*192*64 + (T[ti]*16 + lo)*64 + kc*32 + hi*8);
        wiS[ti][kc] = ld8(WIs, (lS-1)*192*64 + (T[ti]*16 + lo)*64 + kc*32 + hi*8);
      }
#pragma unroll
      for (int kc = 0; kc < 4; ++kc)
        if (kc < nkcF)
          wiF[ti][kc] = ld8(WIF, iF + (T[ti]*16 + lo)*KF + kc*32 + hi*8);
    }
    brz_[0][0] = ld1(bi, lF*192 + T[0]*16 + lo) + ld1(bh, lF*192 + T[0]*16 + lo);
    brz_[0][1] = ld1(bi, lF*192 + T[1]*16 + lo) + ld1(bh, lF*192 + T[1]*16 + lo);
    bin_[0]    = ld1(bi, lF*192 + T[2]*16 + lo);
    bhn_[0]    = ld1(bh, lF*192 + T[2]*16 + lo);
    brz_[1][0] = ld1(bi, lS*192 + T[0]*16 + lo) + ld1(bh, lS*192 + T[0]*16 + lo);
    brz_[1][1] = ld1(bi, lS*192 + T[1]*16 + lo) + ld1(bh, lS*192 + T[1]*16 + lo);
    bin_[1]    = ld1(bi, lS*192 + T[2]*16 + lo);
    bhn_[1]    = ld1(bh, lS*192 + T[2]*16 + lo);
  };
  load_phase(0);
  if (P == 15 && !isX) {   // Wo + bo in registers (projection wave group)
#pragma unroll
    for (int ct = 0; ct < 2; ++ct) {
      int n = 32*qg + 16*ct + lo;
#pragma unroll
      for (int kc = 0; kc < 2; ++kc)
        wo[ct][kc] = ld8(Wo_, n*64 + kc*32 + hi*8);
      bov[ct] = ld1(bo_, n);
    }
  }

  auto do_proj = [&](int tprev, const u16* hs) {   // Y-group; rows 0-7 real
    f32x4 pacc[2];
#pragma unroll
    for (int ct = 0; ct < 2; ++ct) { float v = bov[ct]; f32x4 tv = {v,v,v,v}; pacc[ct] = tv; }
#pragma unroll
    for (int kc = 0; kc < 2; ++kc) {
      short8 hA = *(const short8*)(hs + lo*72 + kc*32 + hi*8);
      pacc[0] = __builtin_amdgcn_mfma_f32_16x16x32_bf16(hA, wo[0][kc], pacc[0], 0, 0, 0);
      pacc[1] = __builtin_amdgcn_mfma_f32_16x16x32_bf16(hA, wo[1][kc], pacc[1], 0, 0, 0);
    }
    if (hi < 2) {
#pragma unroll
      for (int ct = 0; ct < 2; ++ct) {
        int n = 32*qg + 16*ct + lo;
#pragma unroll
        for (int p = 0; p < 4; ++p) {
          int b = 8*g + hi*4 + p;
          size_t idx = ((size_t)b * 256 + (tprev - 256)) * 128 + n;
          float v = fminf(64.f, fmaxf(-64.f, pacc[ct][p]));
          if (bf) ((u16*)out_)[idx] = f2bf(v);
          else    ((float*)out_)[idx] = v;
        }
      }
    }
  };

  // ---- generic GRU cell (register weight fragments; static indexing only)
  auto gcell = [&](const short8 (*wh)[2], const short8 (*wi)[4], int nkc, bool skipx,
                   const short8* xf, const u16* hs,
                   const float* brz, float bin, float bhn, float* hp, u16* ob) {
    f32x4 ar, az, ain, ahn;
    { float v;
      v = brz[0]; ar  = (f32x4){v,v,v,v};
      v = brz[1]; az  = (f32x4){v,v,v,v};
      v = bin;    ain = (f32x4){v,v,v,v};
      v = bhn;    ahn = (f32x4){v,v,v,v}; }
#pragma unroll
    for (int kc = 0; kc < 2; ++kc) {
      short8 hA = *(const short8*)(hs + lo*72 + kc*32 + hi*8);
      ar  = __builtin_amdgcn_mfma_f32_16x16x32_bf16(hA, wh[0][kc], ar,  0, 0, 0);
      az  = __builtin_amdgcn_mfma_f32_16x16x32_bf16(hA, wh[1][kc], az,  0, 0, 0);
      ahn = __builtin_amdgcn_mfma_f32_16x16x32_bf16(hA, wh[2][kc], ahn, 0, 0, 0);
    }
    if (!skipx) {
#pragma unroll
      for (int kc = 0; kc < 4; ++kc) {
        if (kc < nkc) {
          ar  = __builtin_amdgcn_mfma_f32_16x16x32_bf16(xf[kc], wi[0][kc], ar,  0, 0, 0);
          az  = __builtin_amdgcn_mfma_f32_16x16x32_bf16(xf[kc], wi[1][kc], az,  0, 0, 0);
          ain = __builtin_amdgcn_mfma_f32_16x16x32_bf16(xf[kc], wi[2][kc], ain, 0, 0, 0);
        }
      }
    }
#pragma unroll
    for (int p = 0; p < 4; ++p) {
      float r = sigm(ar[p]);
      float z = sigm(az[p]);
      float n = tanhf_(ain[p] + r * ahn[p]);
      float h = n + z * (hp[p] - n);
      h = fminf(1.f, fmaxf(-1.f, h));
      hp[p] = h;
      ob[p] = f2bf(h);
    }
  };
  // zero-pad rows 8-15: every A-operand pad row stays exactly 0 forever
  auto wtile = [&](u16* hd, const u16* ob) {
#pragma unroll
    for (int p = 0; p < 4; ++p)
      hd[(hi*4 + p) * 72 + qg*16 + lo] = (hi < 2) ? ob[p] : (u16)0;
  };
  auto xfrag2 = [&](const u16* xs, short8* xf) {
#pragma unroll
    for (int kc = 0; kc < 2; ++kc)
      xf[kc] = *(const short8*)(xs + lo*72 + kc*32 + hi*8);
  };

  float hpF[4] = {0,0,0,0}, hpS[4] = {0,0,0,0};
  const int brow = 8*g + (lo & 7);   // P0 ctx row (rows 8-15 duplicate rows 0-7)

  const int eIn  = (P > 0 ? P - 1 : 0) * 16 + g;
  const int eOut = (P < 15 ? P : 14) * 16 + g;
  int* fin   = pflag + eIn  * FSTRIDE;
  int* fout  = pflag + eOut * FSTRIDE;
  int* cself = cflag + (P * 16 + g) * FSTRIDE;
  int* cnext = cflag + ((P < 15 ? P + 1 : 15) * 16 + g) * FSTRIDE;

  // ring address of record t (128 u64 per record)
  auto raddr = [&](int t) -> const u64* {
    return (t < 256)
      ? (ringE + (size_t)eIn * ((size_t)RE * 128) + (size_t)(t & (RE-1)) * 128)
      : (ringD + (size_t)eIn * ((size_t)RW * 128) + (size_t)((t-256) & (RW-1)) * 128);
  };
  auto waddr = [&](int t) -> u64* {
    return (t < 256)
      ? (ringE + (size_t)eOut * ((size_t)RE * 128) + (size_t)(t & (RE-1)) * 128)
      : (ringD + (size_t)eOut * ((size_t)RW * 128) + (size_t)((t-256) & (RW-1)) * 128);
  };
  auto stage_x = [&](int t, u64 r) {   // tid<128: u64 idx = col*2+h2 (rows 4h2..)
    u16* xd = xst[t & 1];
    int col = tid >> 1, rb = 4 * (tid & 1);
#pragma unroll
    for (int p = 0; p < 4; ++p) xd[(rb + p) * 72 + col] = (u16)(r >> (16 * p));
  };

  int budget = 1 << 22;   // anti-hang
  int f0=0,f1=0,f2=0,f3=0, c0=0,c1=0,c2=0,c3=0;   // tid0 probe holds (chunk-stale)
  short8 cfx[4] = {zf8, zf8, zf8, zf8};           // P0 ctx prefetch (X)

  __syncthreads();   // buffers visible

  // ---------------- span: slots t = tbase..tbase+255 (X: c0,c1(t); Y: c2,c3(t-1))
  auto span = [&](const int tbase, const int cbase, const int RC, const bool dec) {
    const int NC = 256 / CH;
    const bool credOn = (RC < NC);

    // ---- prologue: wait flag >= cbase+1 (=> records <= tbase) + stage x(tbase)
    if (P > 0) {
      if (tid == 0) {
        int v = s_fin;
        if (v < cbase + 1) {
          while (budget > 0) {
            int a = FLD(fin+0), b = FLD(fin+1), c = FLD(fin+2), d = FLD(fin+3);
            v = imin(imin(a, b), imin(c, d));
            if (v >= cbase + 1) break;
            --budget; __builtin_amdgcn_s_sleep(2);
          }
          s_fin = v; f0 = v; f1 = v; f2 = v; f3 = v;
        }
      }
      __syncthreads();
      if (tid < 128) stage_x(tbase, FLD(raddr(tbase) + tid));
    }
    if (P == 0 && isX) {
      int tx = (tbase < 256) ? tbase : 0;
#pragma unroll
      for (int kc = 0; kc < 4; ++kc) cfx[kc] = ld8(ctx_, (brow*256 + tx)*128 + kc*32 + hi*8);
    }

#pragma unroll 1
    for (int k = 0; k < NC; ++k) {
      const int t0 = tbase + k * CH;
      const int ck = cbase + k;
      const int fneed = ck + 2 - ((dec && k == NC - 1) ? 1 : 0);   // chunk-valued
      const int need  = (credOn && k >= RC) ? (ck + 1 - RC) : 0;
      u64 ra[CH];
#pragma unroll
      for (int j = 0; j < CH; ++j) ra[j] = 0;

#pragma unroll
      for (int tt = 0; tt < CH; ++tt) {
        const int t = t0 + tt;
        lds_barrier();   // BAR1: slot start

        if (tt == 0) {
          int vf = s_fin, vc = s_cn;
          const bool slowF = (P > 0)  && (vf < fneed);
          const bool slowC = (P < 15) && (need > 0) && (vc < need);
          if (slowF || slowC) {
            if (tid == 0) {
              if (slowF) {
                int v = 0;
                while (budget > 0) {
                  int a = FLD(fin+0), b = FLD(fin+1), c = FLD(fin+2), d = FLD(fin+3);
                  v = imin(imin(a, b), imin(c, d));
                  if (v >= fneed) break;
                  --budget; __builtin_amdgcn_s_sleep(2);
                }
                s_fin = v; f0 = v; f1 = v; f2 = v; f3 = v;
              }
              if (slowC) {
                int v = 0;
                while (budget > 0) {
                  int a = FLD(cnext+0), b = FLD(cnext+1), c = FLD(cnext+2), d = FLD(cnext+3);
                  v = imin(imin(a, b), imin(c, d));
                  if (v >= need) break;
                  --budget; __builtin_amdgcn_s_sleep(2);
                }
                s_cn = v; c0 = v; c1 = v; c2 = v; c3 = v;
              }
            }
            lds_barrier();
          }
          if (P > 0 && tid < 128) {   // prime records t0+1..t0+CH
#pragma unroll
            for (int j = 0; j < CH; ++j)
              if (t0 + 1 + j <= 511) ra[j] = FLD(raddr(t0 + 1 + j) + tid);
          }
        }

        // ================= phase 1: X c0(t) | Y flag + proj + c2(t-1) ==========
        if (isX) {
          short8 xf[4] = {zf8, zf8, zf8, zf8};
          bool skipx = false;
          if (P > 0) xfrag2(xst[t & 1], xf);
          else { xf[0]=cfx[0]; xf[1]=cfx[1]; xf[2]=cfx[2]; xf[3]=cfx[3]; skipx = (t == 256); }
          u16 ob[4];
          gcell(whF, wiF, NKC0, skipx, xf, hb[0][(t + 1) & 1],
                brz_[0], bin_[0], bhn_[0], hpF, ob);
          wtile(hb[0][t & 1], ob);
        } else {
          if (P < 15 && tt == 0 && k > 0) {   // flag for chunks < ck (records <= t0-2)
            DRAIN0();
            if (lane == 0) FST(fout + qg, ck);
          }
          if (P == 15 && dec && t >= 258) do_proj(t - 2, hb[3][t & 1]);
          if (t - 1 >= tbase) {
            const int s = t - 1;
            short8 xf[4] = {zf8, zf8, zf8, zf8};
            xfrag2(hb[1][s & 1], xf);
            u16 ob[4];
            gcell(whF, wiF, 2, false, xf, hb[2][(s + 1) & 1],
                  brz_[0], bin_[0], bhn_[0], hpF, ob);
            wtile(hb[2][s & 1], ob);
          }
        }

        lds_barrier();   // BAR2: mid-slot

        // ================= phase 2: X c1(t)+stage | Y c3(t-1)+store ============
        if (isX) {
          if (tt == CH - 1 && tid == 0) {   // publish previous probes
            if (P > 0)  s_fin = imin(imin(f0, f1), imin(f2, f3));
            if (P < 15 && credOn) s_cn = imin(imin(c0, c1), imin(c2, c3));
          }
          if (tt == 0 && tid == 0) {        // issue probes (once per chunk)
            if (P > 0)  { f0 = FLD(fin+0); f1 = FLD(fin+1); f2 = FLD(fin+2); f3 = FLD(fin+3); }
            if (P < 15 && credOn) { c0 = FLD(cnext+0); c1 = FLD(cnext+1); c2 = FLD(cnext+2); c3 = FLD(cnext+3); }
          }
          short8 xf[4] = {zf8, zf8, zf8, zf8};
          xfrag2(hb[0][t & 1], xf);
          u16 ob[4];
          gcell(whS, wiS, 2, false, xf, hb[1][(t + 1) & 1],
                brz_[1], bin_[1], bhn_[1], hpS, ob);
          wtile(hb[1][t & 1], ob);
          if (P == 0) {              // prefetch ctx for t+1
            int tn = t + 1;
            if (tn <= 511) {
              int tx = (tn < 256) ? tn : ((tn == 256) ? 0 : tn - 257);
#pragma unroll
              for (int kc = 0; kc < 4; ++kc)
                cfx[kc] = ld8(ctx_, (brow*256 + tx)*128 + kc*32 + hi*8);
            }
          }
          if (P > 0 && t < 511 && tid < 128) stage_x(t + 1, ra[tt]);
          if (tt == CH - 1 && P > 0 && credOn) {   // consumer credit (per X wave)
            DRAIN0();
            if (lane == 0) FST(cself + qg, ck + 1);
          }
        } else {
          if (t - 1 >= tbase) {
            const int s = t - 1;
            short8 xf[4] = {zf8, zf8, zf8, zf8};
            xfrag2(hb[2][s & 1], xf);
            u16 ob[4];
            gcell(whS, wiS, 2, false, xf, hb[3][(s + 1) & 1],
                  brz_[1], bin_[1], bhn_[1], hpS, ob);
            wtile(hb[3][s & 1], ob);
            if (P < 15 && hi < 2) {
              u64 da = (u64)ob[0] | ((u64)ob[1] << 16) | ((u64)ob[2] << 32) | ((u64)ob[3] << 48);
              FST(waddr(s) + (16*qg + lo)*2 + hi, da);
            }
          }
        }
      }
    }

    // ---- tail: Y finishes step tbase+255 (cells 2,3) + final flag
    lds_barrier();
    if (!isX) {
      const int s = tbase + 255;
      short8 xf[4] = {zf8, zf8, zf8, zf8};
      xfrag2(hb[1][s & 1], xf);
      u16 ob[4];
      gcell(whF, wiF, 2, false, xf, hb[2][(s + 1) & 1],
            brz_[0], bin_[0], bhn_[0], hpF, ob);
      wtile(hb[2][s & 1], ob);
    }
    lds_barrier();
    if (!isX) {
      const int s = tbase + 255;
      short8 xf[4] = {zf8, zf8, zf8, zf8};
      xfrag2(hb[2][s & 1], xf);
      u16 ob[4];
      gcell(whS, wiS, 2, false, xf, hb[3][(s + 1) & 1],
            brz_[1], bin_[1], bhn_[1], hpS, ob);
      wtile(hb[3][s & 1], ob);
      if (P < 15) {
        if (hi < 2) {
          u64 da = (u64)ob[0] | ((u64)ob[1] << 16) | ((u64)ob[2] << 32) | ((u64)ob[3] << 48);
          FST(waddr(s) + (16*qg + lo)*2 + hi, da);
        }
        DRAIN0();
        if (lane == 0) FST(fout + qg, cbase + NC);   // all span records visible
      }
    }
  };

  {
    const int NCe = 256 / CH;
    int RCe = (RE >= 256) ? NCe : (RE / CH) - 2; if (RCe < 1) RCe = 1;
    span(0, 0, RCe, false);                        // encoder
    __syncthreads();
    load_phase(1);                                 // decoder weights -> registers
    __syncthreads();
    int RCd = (RW >= 256) ? (256 / CH) : (RW / CH) - 2; if (RCd < 1) RCd = 1;
    span(256, NCe, RCd, true);                     // decoder
  }

  // ---- epilogue: projections of steps 510, 511
  lds_barrier();
  if (P == 15 && !isX) {
    do_proj(510, hb[3][0]);
    do_proj(511, hb[3][1]);
  }
}

extern "C" void kernel_launch(void* const* d_in, const int* in_sizes, int n_in,
                              void* d_out, int out_size, void* d_ws, size_t ws_size,
                              hipStream_t stream)
{
  char* ws = (char*)d_ws;
  int* pflag = (int*)ws;                    // 240 edges x 64B per-wave flag lines
  int* cflag = (int*)(ws + 32768);          // 256 x 64B per-wave credit lines
  char* ringbase = ws + 65536;

  const size_t per_slot = (size_t)15 * 16 * 1024;  // one ring step: 240 edges x 1KB
  size_t avail = (ws_size > 65536) ? ws_size - 65536 : 0;

  int RE, RW;
  u64 *ringE, *ringD;
  int Rh = 0;
  for (int r = 256; r >= 16; r >>= 1)
    if ((size_t)(2 * r) * per_slot <= avail) { Rh = r; break; }
  if (Rh) {                                  // both rings in workspace
    RE = RW = Rh;
    ringE = (u64*)ringbase;
    ringD = (u64*)(ringbase + (size_t)Rh * per_slot);
  } else {                                   // fallback: encoder ring borrows d_out
    int Rw = 1;
    for (int r = 256; r >= 1; r >>= 1)
      if ((size_t)r * per_slot <= avail) { Rw = r; break; }
    RW = Rw;
    int Re = 1;
    for (int r = 16; r >= 1; r >>= 1)
      if ((size_t)r * per_slot <= (size_t)out_size) { Re = r; break; }
    RE = Re;
    ringE = (u64*)d_out;
    ringD = (u64*)ringbase;
  }

  hipMemsetAsync(ws, 0, 65536, stream);     // zero flags every launch

  gru_pipeline<<<256, 512, 0, stream>>>(
      d_in[0], d_in[1], d_in[2], d_in[3], d_in[4], d_in[5],
      d_in[6], d_in[7], d_in[8], d_in[9], d_in[10], d_in[11], d_in[12],
      d_out, pflag, cflag, ringE, ringD, RE, RW);
  (void)in_sizes; (void)n_in;
}